// Round 6
// baseline (2165.304 us; speedup 1.0000x reference)
//
#include <hip/hip_runtime.h>
#include <math.h>

// ConvGRU fused per-timestep kernel, v5: occupancy-first.
// x: (4,16,64,64,64) f32, Wx: (96,16,3,3), bx: (96), Wh: (96,32,3,3).
// r-gate is dead in the reference: only gate rows [0,32) (z) and [64,96) (n).
// Thread = 2 horizontal pixels x 1 output channel (4 accs). Block = 8x64 tile.
// Grid (8,32,4) = 1024 blocks -> 4 blocks/CU, 16 waves/CU (2x R1-R4's pool).
// Inputs staged in LDS in 6 chunks of 8 channels (10 halo rows); weights for
// this block's channel staged to LDS once. h ping-pongs d_out <-> d_ws;
// t=63 writes d_out.

#define LW 72
#define DOFF 4
#define CROWS 10                       // 8 tile rows + 2 halo
#define PIX_FLOATS (8 * CROWS * LW)    // 5760 floats = 23 KB
#define WPAD 12                        // filter padded 9 -> 12 floats
#define W_FLOATS (6 * 8 * 2 * WPAD)    // 1152 floats = 4.6 KB

__global__ __launch_bounds__(256, 4) void convgru_step(
    const float* __restrict__ x, const float* __restrict__ Wx,
    const float* __restrict__ bx, const float* __restrict__ Wh,
    const float* __restrict__ hsrc, float* __restrict__ hdst, int t)
{
    __shared__ float plds[PIX_FLOATS];
    __shared__ float wlds[W_FLOATS];
    const int tx  = threadIdx.x;
    const int y0  = blockIdx.x * 8;        // tile rows y0..y0+7
    const int oc  = blockIdx.y;            // output channel (uniform)
    const int b   = blockIdx.z;
    const int r   = tx >> 5;               // 0..7: output row y0+r
    const int x0  = (tx & 31) * 2;         // output cols x0, x0+1

    // prefetch h_prev for the 2 output pixels (coalesced float2)
    const size_t obase = (size_t)(b * 32 + oc) * 4096 + (y0 + r) * 64 + x0;
    float2 hprev = *(const float2*)(hsrc + obase);

    // ---- one-time: stage this channel's weights into LDS ----
    // layout: wlds[((chunk*8 + cin8)*2 + gate)*WPAD + tap], tap 9..11 = pad
    for (int i = tx; i < W_FLOATS; i += 256) {
        int tap  = i % WPAD;
        int rest = i / WPAD;
        int gate = rest & 1;  rest >>= 1;
        int cin8 = rest & 7;
        int chunk = rest >> 3;
        float val = 0.0f;
        if (tap < 9) {
            int grow = (gate ? 64 + oc : oc);
            if (chunk < 2)
                val = Wx[((size_t)grow * 16 + chunk * 8 + cin8) * 9 + tap];
            else
                val = Wh[((size_t)grow * 32 + (chunk - 2) * 8 + cin8) * 9 + tap];
        }
        wlds[i] = val;
    }

    // zero halo columns once (80 rows x 2 cols = 160 entries)
    if (tx < 160)
        plds[(tx >> 1) * LW + ((tx & 1) ? (DOFF + 64) : (DOFF - 1))] = 0.0f;

    const float bz = bx[oc], bn = bx[64 + oc];
    float az0 = bz, az1 = bz, an0 = bn, an1 = bn;

    for (int chunk = 0; chunk < 6; ++chunk) {
        const float* src;
        size_t chanStride;
        if (chunk < 2) {
            src = x + ((size_t)(b * 16 + chunk * 8) * 64 + t) * 4096;
            chanStride = (size_t)64 * 4096;
        } else {
            src = hsrc + (size_t)(b * 32 + (chunk - 2) * 8) * 4096;
            chanStride = 4096;
        }

        __syncthreads();  // prev compute (or weight/halo staging) done
        // stage 8 channels x 10 halo rows x 64 cols as float4 (1280 tasks)
        #pragma unroll
        for (int i = 0; i < 5; ++i) {
            int task = i * 256 + tx;
            int f4   = task & 15;
            int rowg = task >> 4;          // 0..79 = ch*10 + rr
            int ch   = rowg / CROWS;
            int rr   = rowg - ch * CROWS;
            int yy   = y0 - 1 + rr;
            float4 v = make_float4(0.f, 0.f, 0.f, 0.f);
            if ((unsigned)yy < 64u)
                v = *(const float4*)(src + ch * chanStride + yy * 64 + f4 * 4);
            *(float4*)&plds[rowg * LW + DOFF + f4 * 4] = v;   // 16B-aligned
        }
        __syncthreads();

        #pragma unroll
        for (int cin = 0; cin < 8; ++cin) {
            // 3 rows x 4 cols neighborhood for pixels (y0+r, x0) and (y0+r, x0+1)
            const float* lb = &plds[(cin * CROWS + r) * LW + DOFF + x0];
            float v[3][4];
            #pragma unroll
            for (int kr = 0; kr < 3; ++kr) {
                v[kr][0] = lb[kr * LW - 1];
                v[kr][1] = lb[kr * LW];
                v[kr][2] = lb[kr * LW + 1];
                v[kr][3] = lb[kr * LW + 2];
            }
            const float* wz = &wlds[((chunk * 8 + cin) * 2 + 0) * WPAD];
            const float* wn = &wlds[((chunk * 8 + cin) * 2 + 1) * WPAD];
            #pragma unroll
            for (int kr = 0; kr < 3; ++kr) {
                #pragma unroll
                for (int kc = 0; kc < 3; ++kc) {
                    const float wzv = wz[kr * 3 + kc];
                    const float wnv = wn[kr * 3 + kc];
                    az0 = fmaf(v[kr][kc],     wzv, az0);
                    az1 = fmaf(v[kr][kc + 1], wzv, az1);
                    an0 = fmaf(v[kr][kc],     wnv, an0);
                    an1 = fmaf(v[kr][kc + 1], wnv, an1);
                }
            }
        }
    }

    float z0 = 1.0f / (1.0f + __expf(-az0));
    float z1 = 1.0f / (1.0f + __expf(-az1));
    float e0 = __expf(2.0f * an0), e1 = __expf(2.0f * an1);
    float n0 = 1.0f - 2.0f / (e0 + 1.0f);
    float n1 = 1.0f - 2.0f / (e1 + 1.0f);
    float2 outv;
    outv.x = (1.0f - z0) * hprev.x + z0 * n0;
    outv.y = (1.0f - z1) * hprev.y + z1 * n1;
    *(float2*)(hdst + obase) = outv;
}

extern "C" void kernel_launch(void* const* d_in, const int* in_sizes, int n_in,
                              void* d_out, int out_size, void* d_ws, size_t ws_size,
                              hipStream_t stream) {
    const float* x  = (const float*)d_in[0];
    const float* Wx = (const float*)d_in[1];
    const float* bx = (const float*)d_in[2];
    const float* Wh = (const float*)d_in[3];
    float* out = (float*)d_out;
    float* ws  = (float*)d_ws;

    // h0 = zeros in d_out (even t: read out -> write ws; odd t: read ws -> write out;
    // t=63 odd => final h lands in d_out).
    hipMemsetAsync(d_out, 0, (size_t)524288 * sizeof(float), stream);

    dim3 grid(8, 32, 4), block(256);
    for (int t = 0; t < 64; ++t) {
        const float* src = (t & 1) ? ws : out;
        float*       dst = (t & 1) ? out : ws;
        hipLaunchKernelGGL(convgru_step, grid, block, 0, stream,
                           x, Wx, bx, Wh, src, dst, t);
    }
}

// Round 7
// 695.539 us; speedup vs baseline: 3.1131x; 3.1131x over previous
//
#include <hip/hip_runtime.h>
#include <math.h>

// ConvGRU v6: MFMA implicit-GEMM per timestep.
// x: (4,16,64,64,64) f32, Wx: (96,16,3,3), bx: (96), Wh: (96,32,3,3).
// r-gate dead -> M = 32 oc x 2 gates arranged as rows [z oc0-15, n oc0-15] per
// mtile so z/n for one oc land in the same lane (C rows r and r+16 = regs r, r+8).
// K = 48 cin x 12 (9 taps + 3 zero-weight phantoms) = 576 = 36 chunks of 16.
// Pair trick: k-pairs (2j,2j+1) always map to adjacent staged cols -> B-frag
// regs come from ds_read_b32 (+v_alignbit for even-x lanes). A-frags (weights)
// prearranged once by build_wfrag into d_ws (fp16, frag layout), loaded per
// chunk via coalesced global dwordx4 (L2-hot, vmcnt pipe).
// Block = 4 waves = one (b,y) row: all 64 px x all 32 oc; stage once per step.
// h (fp32) ping-pongs d_out <-> d_ws; t=63 writes d_out.

typedef _Float16 half8 __attribute__((ext_vector_type(8)));
typedef float floatx16 __attribute__((ext_vector_type(16)));

#define NROWS 144          // 48 cin * 3 ky
#define RSTRIDE 136        // bytes per LDS row: cols -2..65 as f16 (68*2)
#define LDS_DW ((NROWS * RSTRIDE + 16) / 4)   // + pad for tail d2 reads

static __device__ __forceinline__ unsigned pack2(float a, float b) {
    _Float16 ha = (_Float16)a, hb = (_Float16)b;
    unsigned short ua = *(unsigned short*)&ha, ub = *(unsigned short*)&hb;
    return (unsigned)ua | ((unsigned)ub << 16);
}

// ---- pre-kernel: weights -> A-fragment layout ----
// wfrag[(mtile*36 + chunk)*64 + lane] = 8 f16, k = chunk*16 + (lane>>5)*8 + j
__global__ __launch_bounds__(64) void build_wfrag(
    const float* __restrict__ Wx, const float* __restrict__ Wh,
    uint4* __restrict__ wfrag)
{
    const int bid   = blockIdx.x;            // 0..71
    const int mtile = bid / 36, chunk = bid % 36;
    const int lane  = threadIdx.x;
    const int m     = lane & 31;
    const int grow  = (m < 16) ? (mtile * 16 + m) : (64 + mtile * 16 + (m - 16));
    unsigned short h[8];
    for (int j = 0; j < 8; ++j) {
        int k   = chunk * 16 + (lane >> 5) * 8 + j;
        int cin = k / 12, t12 = k - cin * 12;
        int p = t12 >> 1, o = t12 & 1;
        int ky = p >> 1, q = p & 1;
        int kx = q ? (2 + o) : o;            // q=1,o=1 -> phantom (w=0)
        float w = 0.0f;
        if (!(q && o)) {
            if (cin < 16) w = Wx[((size_t)grow * 16 + cin) * 9 + ky * 3 + kx];
            else          w = Wh[((size_t)grow * 32 + (cin - 16)) * 9 + ky * 3 + kx];
        }
        _Float16 hw = (_Float16)w;
        h[j] = *(unsigned short*)&hw;
    }
    uint4 o4;
    o4.x = (unsigned)h[0] | ((unsigned)h[1] << 16);
    o4.y = (unsigned)h[2] | ((unsigned)h[3] << 16);
    o4.z = (unsigned)h[4] | ((unsigned)h[5] << 16);
    o4.w = (unsigned)h[6] | ((unsigned)h[7] << 16);
    wfrag[(size_t)bid * 64 + lane] = o4;
}

__global__ __launch_bounds__(256, 1) void convgru_step(
    const float* __restrict__ x, const float* __restrict__ bx,
    const uint4* __restrict__ wfrag,
    const float* __restrict__ hsrc, float* __restrict__ hdst, int t)
{
    __shared__ unsigned int plds[LDS_DW];
    const int tx = threadIdx.x;
    const int y  = blockIdx.x;               // image row 0..63
    const int b  = blockIdx.y;               // batch 0..3

    // ---- stage 48 cin x 3 halo rows x 64 cols -> fp16 LDS (cols -2..65) ----
    // row rr = cin*3 + ky; col c at byte rr*RSTRIDE + 2*(c+2).
    if (tx < NROWS) {                        // halo cols -2,-1 and 64,65 = 0
        plds[tx * 34]      = 0u;
        plds[tx * 34 + 33] = 0u;
    }
    #pragma unroll
    for (int i = 0; i < 9; ++i) {            // 2304 quad-tasks
        int task = i * 256 + tx;
        int rr   = task >> 4;                // 0..143
        int qd   = task & 15;                // col group: cols 4qd..4qd+3
        int cin  = rr / 3;
        int ky   = rr - cin * 3;
        int ys   = y + ky - 1;
        float4 v = make_float4(0.f, 0.f, 0.f, 0.f);
        if ((unsigned)ys < 64u) {
            const float* src = (cin < 16)
                ? x + (((size_t)(b * 16 + cin) * 64 + t) * 4096)
                : hsrc + ((size_t)(b * 32 + (cin - 16)) * 4096);
            v = *(const float4*)(src + ys * 64 + qd * 4);
        }
        plds[rr * 34 + 2 * qd + 1] = pack2(v.x, v.y);
        plds[rr * 34 + 2 * qd + 2] = pack2(v.z, v.w);
    }
    __syncthreads();

    // ---- GEMM: each wave one 32x32 C-tile ----
    const int lane  = tx & 63;
    const int wv    = tx >> 6;
    const int mtile = wv & 1;                // oc group 0-15 / 16-31
    const int ntile = wv >> 1;               // px cols 0-31 / 32-63
    const int xpx   = ntile * 32 + (lane & 31);
    const int half  = lane >> 5;
    const bool par  = (xpx & 1) != 0;        // odd x: pairs already aligned
    // per-lane byte base: window start + half-selected row pair (R0 = c*4+2h)
    const int basev = ((2 * xpx + 2) & ~3) + half * (2 * RSTRIDE);
    const char* lb  = (const char*)plds + basev;

    floatx16 acc;
    #pragma unroll
    for (int i = 0; i < 16; ++i) acc[i] = 0.0f;

    #pragma unroll
    for (int c = 0; c < 36; ++c) {
        uint4 aw = wfrag[(size_t)((mtile * 36 + c) * 64 + lane)];
        const int B0 = c * 4 * RSTRIDE;      // row R0 byte offset (static)
        unsigned d0 = *(const unsigned*)(lb + B0);
        unsigned d1 = *(const unsigned*)(lb + B0 + 4);
        unsigned d2 = *(const unsigned*)(lb + B0 + 8);
        unsigned e0 = *(const unsigned*)(lb + B0 + RSTRIDE);
        unsigned e1 = *(const unsigned*)(lb + B0 + RSTRIDE + 4);
        unsigned e2 = *(const unsigned*)(lb + B0 + RSTRIDE + 8);
        uint4 bf;
        bf.x = par ? d0 : ((d0 >> 16) | (d1 << 16));
        bf.y = par ? d1 : ((d1 >> 16) | (d2 << 16));
        bf.z = par ? e0 : ((e0 >> 16) | (e1 << 16));
        bf.w = par ? e1 : ((e1 >> 16) | (e2 << 16));
        union { uint4 u; half8 h; } ua, ub;
        ua.u = aw; ub.u = bf;
        acc = __builtin_amdgcn_mfma_f32_32x32x16_f16(ua.h, ub.h, acc, 0, 0, 0);
    }

    // ---- epilogue: rows r (z) and r+16 (n) of C are regs r, r+8 (same lane) ----
    #pragma unroll
    for (int r = 0; r < 8; ++r) {
        const int row = (r & 3) + 8 * (r >> 2) + 4 * half;   // 0..15
        const int oc  = mtile * 16 + row;
        const size_t a = (size_t)(b * 32 + oc) * 4096 + y * 64 + xpx;
        float zp = acc[r]     + bx[oc];
        float np = acc[r + 8] + bx[64 + oc];
        float hp = hsrc[a];
        float z  = 1.0f / (1.0f + __expf(-zp));
        float e  = __expf(2.0f * np);
        float n  = 1.0f - 2.0f / (e + 1.0f);                 // tanh
        hdst[a] = (1.0f - z) * hp + z * n;
    }
}

extern "C" void kernel_launch(void* const* d_in, const int* in_sizes, int n_in,
                              void* d_out, int out_size, void* d_ws, size_t ws_size,
                              hipStream_t stream) {
    const float* x  = (const float*)d_in[0];
    const float* Wx = (const float*)d_in[1];
    const float* bx = (const float*)d_in[2];
    const float* Wh = (const float*)d_in[3];
    float* out = (float*)d_out;
    float* hws = (float*)d_ws;                               // 2 MB h buffer
    uint4* wfrag = (uint4*)((char*)d_ws + (4u << 20));       // 74 KB A-frags

    // h0 = zeros in d_out (even t: read out -> write ws; odd t: read ws -> out;
    // t=63 odd => final h lands in d_out).
    hipMemsetAsync(d_out, 0, (size_t)524288 * sizeof(float), stream);
    hipLaunchKernelGGL(build_wfrag, dim3(72), dim3(64), 0, stream, Wx, Wh, wfrag);

    dim3 grid(64, 4), block(256);
    for (int t = 0; t < 64; ++t) {
        const float* src = (t & 1) ? hws : out;
        float*       dst = (t & 1) ? out : hws;
        hipLaunchKernelGGL(convgru_step, grid, block, 0, stream,
                           x, bx, wfrag, src, dst, t);
    }
}